// Round 5
// baseline (682.972 us; speedup 1.0000x reference)
//
#include <hip/hip_runtime.h>
#include <hip/hip_bf16.h>

#define S_LEN 2048
#define D_DIM 128
#define BH_N  64
#define BR    64
#define BC    64
#define NTILE (S_LEN / BC)
#define SCALE 0.08838834764831845f
#define WB    256
#define SD    (S_LEN * D_DIM)
#define LSUM_BYTES (BH_N * S_LEN * 4)
#define WS_NEED (LSUM_BYTES + (size_t)BH_N * SD * 2)

typedef __attribute__((ext_vector_type(8)))  short short8;
typedef __attribute__((ext_vector_type(16))) float f32x16;
typedef __attribute__((ext_vector_type(4)))  float fv4;

__device__ __forceinline__ ushort f2bf(float f) {
  union { float f; unsigned u; } x; x.f = f;
  unsigned r = x.u + 0x7FFFu + ((x.u >> 16) & 1u);
  return (ushort)(r >> 16);
}

__device__ __forceinline__ short8 pack8(float4 a, float4 b) {
  short8 p;
  p[0] = (short)f2bf(a.x); p[1] = (short)f2bf(a.y);
  p[2] = (short)f2bf(a.z); p[3] = (short)f2bf(a.w);
  p[4] = (short)f2bf(b.x); p[5] = (short)f2bf(b.y);
  p[6] = (short)f2bf(b.z); p[7] = (short)f2bf(b.w);
  return p;
}

// ===================== Kernel 0: K fp32 -> bf16 (RNE, = f2bf) ================
__global__ __launch_bounds__(256) void cvt_k_kernel(
    const float* __restrict__ k, ushort* __restrict__ kb) {
  size_t total = (size_t)BH_N * SD / 8;
  for (size_t i = (size_t)blockIdx.x * 256 + threadIdx.x; i < total;
       i += (size_t)gridDim.x * 256) {
    float4 a = *(const float4*)(k + i * 8);
    float4 b = *(const float4*)(k + i * 8 + 4);
    *(short8*)(kb + i * 8) = pack8(a, b);
  }
}

// ============================ Kernel A: flash ctx + l ========================
template <bool KB16>
__global__ __launch_bounds__(256, 2) void attn_flash_kernel(
    const float* __restrict__ q, const float* __restrict__ k,
    const ushort* __restrict__ kb, const float* __restrict__ v,
    float* __restrict__ ctx, float* __restrict__ lsum_out) {
  __shared__ __align__(16) char klds[BC * 256];
  __shared__ __align__(16) char vtlds[D_DIM * 128];
  __shared__ __align__(16) char plds[BR * 128];
  __shared__ float lred[2][BR];

  const int tid  = threadIdx.x;
  const int lane = tid & 63;
  const int w    = tid >> 6;
  const int wq   = w >> 1, wk = w & 1;
  const int l31  = lane & 31, lhi = lane >> 5;

  const int bid = blockIdx.x;
  const int qb  = (NTILE - 1) - (bid >> 6);
  const int bh  = bid & 63;

  const float*  qbase  = q  + (size_t)bh * SD;
  const float*  kbase  = k  + (size_t)bh * SD;
  const ushort* kbbase = kb + (size_t)bh * SD;
  const float*  vbase  = v  + (size_t)bh * SD;

  short8 qf[8];
  {
    const float* qrow = qbase + (size_t)(qb * BR + wq * 32 + l31) * D_DIM;
    #pragma unroll
    for (int s = 0; s < 8; ++s) {
      int d0 = 16 * s + 8 * lhi;
      float4 a = *(const float4*)(qrow + d0);
      float4 b = *(const float4*)(qrow + d0 + 4);
      qf[s] = pack8(a, b);
    }
  }

  float4 kreg[8], vreg[8];
  short8 kreg16[4];

  auto load_k = [&](int kt) {
    int trow = tid >> 2, tc = tid & 3;
    if constexpr (KB16) {
      const ushort* src = kbbase + (size_t)(kt * BC + trow) * D_DIM;
      #pragma unroll
      for (int i = 0; i < 4; ++i)
        kreg16[i] = *(const short8*)(src + tc * 8 + i * 32);
    } else {
      const float* src = kbase + (size_t)(kt * BC + trow) * D_DIM;
      #pragma unroll
      for (int i = 0; i < 4; ++i) {
        int c0 = tc * 8 + i * 32;
        kreg[2 * i]     = *(const float4*)(src + c0);
        kreg[2 * i + 1] = *(const float4*)(src + c0 + 4);
      }
    }
  };
  auto write_k = [&]() {
    int trow = tid >> 2, tc = tid & 3;
    #pragma unroll
    for (int i = 0; i < 4; ++i) {
      int c0 = tc * 8 + i * 32;
      int off = (trow * 256 + c0 * 2) ^ ((trow & 7) << 4);
      if constexpr (KB16)
        *(short8*)(klds + off) = kreg16[i];
      else
        *(short8*)(klds + off) = pack8(kreg[2 * i], kreg[2 * i + 1]);
    }
  };
  auto load_v = [&](int kt) {
    int kp = tid & 31, dg = tid >> 5;
    const float* r0 = vbase + (size_t)(kt * BC + 2 * kp) * D_DIM + dg * 16;
    #pragma unroll
    for (int i = 0; i < 4; ++i) {
      vreg[i]     = *(const float4*)(r0 + 4 * i);
      vreg[4 + i] = *(const float4*)(r0 + D_DIM + 4 * i);
    }
  };
  auto write_v = [&]() {
    int kp = tid & 31, dg = tid >> 5;
    #pragma unroll
    for (int j = 0; j < 16; ++j) {
      int d = dg * 16 + j;
      float lo = vreg[j >> 2][j & 3];
      float hi = vreg[4 + (j >> 2)][j & 3];
      unsigned u = (unsigned)f2bf(lo) | ((unsigned)f2bf(hi) << 16);
      int off = (d * 128 + kp * 4) ^ ((d & 7) << 4);
      *(unsigned*)(vtlds + off) = u;
    }
  };

  auto compute_s = [&]() -> f32x16 {
    f32x16 acc;
    #pragma unroll
    for (int i = 0; i < 16; ++i) acc[i] = 0.f;
    int krow = wk * 32 + l31;
    int base = krow * 256;
    int swz  = (krow & 7) << 4;
    #pragma unroll
    for (int s = 0; s < 8; ++s) {
      int off = (base + 32 * s + 16 * lhi) ^ swz;
      short8 kf = *(const short8*)(klds + off);
      acc = __builtin_amdgcn_mfma_f32_32x32x16_bf16(qf[s], kf, acc, 0, 0, 0);
    }
    return acc;
  };

  float l_lane[16];
  f32x16 o0, o1;
  #pragma unroll
  for (int i = 0; i < 16; ++i) { l_lane[i] = 0.f; o0[i] = 0.f; o1[i] = 0.f; }

  load_k(0); load_v(0);

  for (int kt = 0; kt <= qb; ++kt) {
    write_k(); write_v();
    if (kt < qb) { load_k(kt + 1); load_v(kt + 1); }
    __syncthreads();

    f32x16 acc = compute_s();
    int kcol_l = wk * 32 + l31;
    int kcol = kt * BC + kcol_l;
    bool diag = (kt == qb);
    #pragma unroll
    for (int r = 0; r < 16; ++r) {
      int rl = wq * 32 + (r & 3) + 8 * (r >> 2) + 4 * lhi;
      int qrow = qb * BR + rl;
      float e = (diag && kcol > qrow) ? 0.f : __expf(acc[r] * SCALE);
      l_lane[r] += e;
      int poff = (rl * 128 + kcol_l * 2) ^ ((rl & 7) << 4);
      *(ushort*)(plds + poff) = f2bf(e);
    }
    __syncthreads();

    #pragma unroll
    for (int s = 0; s < 4; ++s) {
      int prow = wq * 32 + l31;
      int paoff = (prow * 128 + (16 * s + 8 * lhi) * 2) ^ ((prow & 7) << 4);
      short8 pa = *(const short8*)(plds + paoff);
      int kko = (16 * s + 8 * lhi) * 2;
      int d0 = wk * 64 + l31;
      int d1 = d0 + 32;
      int off0 = (d0 * 128 + kko) ^ ((d0 & 7) << 4);
      int off1 = (d1 * 128 + kko) ^ ((d1 & 7) << 4);
      short8 vb0 = *(const short8*)(vtlds + off0);
      short8 vb1 = *(const short8*)(vtlds + off1);
      o0 = __builtin_amdgcn_mfma_f32_32x32x16_bf16(pa, vb0, o0, 0, 0, 0);
      o1 = __builtin_amdgcn_mfma_f32_32x32x16_bf16(pa, vb1, o1, 0, 0, 0);
    }
    __syncthreads();
  }

  #pragma unroll
  for (int r = 0; r < 16; ++r) {
    float x = l_lane[r];
    x += __shfl_xor(x, 1);  x += __shfl_xor(x, 2);  x += __shfl_xor(x, 4);
    x += __shfl_xor(x, 8);  x += __shfl_xor(x, 16);
    l_lane[r] = x;
  }
  if (l31 == 0) {
    #pragma unroll
    for (int r = 0; r < 16; ++r) {
      int rl = wq * 32 + (r & 3) + 8 * (r >> 2) + 4 * lhi;
      lred[wk][rl] = l_lane[r];
    }
  }
  __syncthreads();

  if (tid < BR)
    lsum_out[(size_t)bh * S_LEN + qb * BR + tid] = lred[0][tid] + lred[1][tid];

  float inv_l[16];
  #pragma unroll
  for (int r = 0; r < 16; ++r) {
    int rl = wq * 32 + (r & 3) + 8 * (r >> 2) + 4 * lhi;
    inv_l[r] = 1.0f / (lred[0][rl] + lred[1][rl]);
  }
  #pragma unroll
  for (int r = 0; r < 16; ++r) {
    int rl = wq * 32 + (r & 3) + 8 * (r >> 2) + 4 * lhi;
    size_t obase = (size_t)(bh * S_LEN + qb * BR + rl) * D_DIM;
    ctx[obase + wk * 64 + l31]      = o0[r] * inv_l[r];
    ctx[obase + wk * 64 + 32 + l31] = o1[r] * inv_l[r];
  }
}

// ================= Kernel B1: one 64x256 weights slab per block ==============
template <bool KB16>
__global__ __launch_bounds__(256, 2) void attn_wts_slab_kernel(
    const float* __restrict__ q, const float* __restrict__ k,
    const ushort* __restrict__ kb, const float* __restrict__ lsum,
    float* __restrict__ wts) {
  __shared__ __align__(16) float pslab[64 * WB];   // 64 KB

  const int bid   = blockIdx.x;
  const int s     = bid & 7;
  const int panel = (bid >> 3) & 31;
  const int bh    = bid >> 8;
  if (s > (panel >> 2)) return;            // fully-masked slab: B2 handles it

  const int tid  = threadIdx.x;
  const int lane = tid & 63;
  const int w    = tid >> 6;
  const int wq   = w >> 1, wk = w & 1;
  const int l31  = lane & 31, lhi = lane >> 5;

  const int rowmax = panel * BR + BR - 1;
  float* wtile = wts + ((size_t)(bh * S_LEN + panel * BR)) * S_LEN + s * WB;

  short8 qf[8];
  {
    const float* qrow = q + (size_t)(bh * S_LEN + panel * BR + wq * 32 + l31) * D_DIM;
    #pragma unroll
    for (int i = 0; i < 8; ++i) {
      int d0 = 16 * i + 8 * lhi;
      float4 a = *(const float4*)(qrow + d0);
      float4 b = *(const float4*)(qrow + d0 + 4);
      qf[i] = pack8(a, b);
    }
  }

  float invl[16];
  #pragma unroll
  for (int r = 0; r < 16; ++r) {
    int rl = wq * 32 + (r & 3) + 8 * (r >> 2) + 4 * lhi;
    invl[r] = 1.0f / lsum[(size_t)bh * S_LEN + panel * BR + rl];
  }

  #pragma unroll
  for (int cb = 0; cb < 4; ++cb) {
    const int colb = s * WB + wk * 128 + cb * 32;
    const int col_local = wk * 128 + cb * 32 + l31;
    if (colb > rowmax) {
      #pragma unroll
      for (int r = 0; r < 16; ++r) {
        int rl = wq * 32 + (r & 3) + 8 * (r >> 2) + 4 * lhi;
        pslab[rl * WB + col_local] = 0.f;
      }
      continue;
    }
    f32x16 acc;
    #pragma unroll
    for (int i = 0; i < 16; ++i) acc[i] = 0.f;
    if constexpr (KB16) {
      const ushort* krow = kb + (size_t)bh * SD + (size_t)(colb + l31) * D_DIM;
      #pragma unroll
      for (int s8 = 0; s8 < 8; ++s8) {
        short8 kf = *(const short8*)(krow + 16 * s8 + 8 * lhi);
        acc = __builtin_amdgcn_mfma_f32_32x32x16_bf16(qf[s8], kf, acc, 0, 0, 0);
      }
    } else {
      const float* krow = k + (size_t)bh * SD + (size_t)(colb + l31) * D_DIM;
      #pragma unroll
      for (int s8 = 0; s8 < 8; ++s8) {
        int d0 = 16 * s8 + 8 * lhi;
        float4 a = *(const float4*)(krow + d0);
        float4 b = *(const float4*)(krow + d0 + 4);
        short8 kf = pack8(a, b);
        acc = __builtin_amdgcn_mfma_f32_32x32x16_bf16(qf[s8], kf, acc, 0, 0, 0);
      }
    }
    const int cg = colb + l31;
    #pragma unroll
    for (int r = 0; r < 16; ++r) {
      int rl = wq * 32 + (r & 3) + 8 * (r >> 2) + 4 * lhi;
      int rowg = panel * BR + rl;
      float p = (cg > rowg) ? 0.f : __expf(acc[r] * SCALE) * invl[r];
      pslab[rl * WB + col_local] = p;
    }
  }
  __syncthreads();
  // drain: each wave streams one 1 KB row per pass (nontemporal)
  #pragma unroll
  for (int pass = 0; pass < 16; ++pass) {
    int row = pass * 4 + w;
    fv4 val = *(const fv4*)&pslab[row * WB + lane * 4];
    __builtin_nontemporal_store(val, (fv4*)(wtile + (size_t)row * S_LEN + lane * 4));
  }
}

// ================= Kernel B2: zero-fill masked slabs (streaming) =============
__global__ __launch_bounds__(256) void attn_wts_zero_kernel(float* __restrict__ wts) {
  const int bid   = blockIdx.x;
  const int bh    = bid & 63;
  const int panel = bid >> 6;                // panel 0 first: most zero work
  const int s0    = (panel >> 2) + 1;
  const int tid   = threadIdx.x;
  const int lane  = tid & 63;
  const int w     = tid >> 6;

  float* wtile = wts + ((size_t)(bh * S_LEN + panel * BR)) * S_LEN;
  fv4 z = (fv4)0.f;
  for (int s = s0; s < S_LEN / WB; ++s) {
    #pragma unroll
    for (int pass = 0; pass < 16; ++pass) {
      int row = pass * 4 + w;
      __builtin_nontemporal_store(
          z, (fv4*)(wtile + (size_t)row * S_LEN + s * WB + lane * 4));
    }
  }
}

extern "C" void kernel_launch(void* const* d_in, const int* in_sizes, int n_in,
                              void* d_out, int out_size, void* d_ws, size_t ws_size,
                              hipStream_t stream) {
  const float* q = (const float*)d_in[0];
  const float* k = (const float*)d_in[1];
  const float* v = (const float*)d_in[2];
  float* ctx = (float*)d_out;
  float* wts = ctx + (size_t)BH_N * SD;
  float*  lsum = (float*)d_ws;
  ushort* kb16 = (ushort*)((char*)d_ws + LSUM_BYTES);

  const bool fast = ws_size >= WS_NEED;

  if (fast) {
    cvt_k_kernel<<<dim3(2048), dim3(256), 0, stream>>>(k, kb16);
    attn_flash_kernel<true><<<dim3(BH_N * NTILE), dim3(256), 0, stream>>>(
        q, k, kb16, v, ctx, lsum);
    attn_wts_slab_kernel<true><<<dim3(BH_N * NTILE * 8), dim3(256), 0, stream>>>(
        q, k, kb16, lsum, wts);
  } else {
    attn_flash_kernel<false><<<dim3(BH_N * NTILE), dim3(256), 0, stream>>>(
        q, k, kb16, v, ctx, lsum);
    attn_wts_slab_kernel<false><<<dim3(BH_N * NTILE * 8), dim3(256), 0, stream>>>(
        q, k, kb16, lsum, wts);
  }
  attn_wts_zero_kernel<<<dim3(BH_N * NTILE), dim3(256), 0, stream>>>(wts);
}